// Round 6
// baseline (479.401 us; speedup 1.0000x reference)
//
#include <hip/hip_runtime.h>
#include <math.h>

#define NMELS   128
#define NFRAMES 626
#define NPAIRS  313
#define NBATCH  32
#define LSAMP   160000
#define NFREQ   513                         // 1024/2 + 1
#define PPB     4                           // frame-pairs per block (1 per wave)
#define NBLK    ((NPAIRS + PPB - 1) / PPB)  // 79
#define NCHUNK  NBLK                        // pcen chunk = 8 frames = 1 block

struct Bins { int v[NMELS + 2]; };          // 130 ints = 520 B kernarg

// reflect-pad index (np.pad mode='reflect', no edge repeat)
__device__ __forceinline__ int refl(int i) {
    if (i < 0) i = -i;
    else if (i >= LSAMP) i = 2 * LSAMP - 2 - i;
    return i;
}

// lane r -> band for sub-iteration i. Pairs wide (high-m) with narrow (low-m)
// bands so per-i loop trip counts are near-uniform across the wave (mel band
// widths grow ~geometrically; the old {r,32+r,64+r,96+r} map made the wave
// wait on the widest lane: ~112 exec-masked iterations vs ~40 balanced).
// Bijective cover of 0..127. Verified win: R2->R4 119.2->109.3 us.
__device__ __forceinline__ int band_of(int i, int r) {
    switch (i) {
        case 0:  return r;
        case 1:  return 127 - r;
        case 2:  return 32 + r;
        default: return 95 - r;
    }
}

__device__ __forceinline__ float2 cadd(float2 a, float2 b){return make_float2(a.x+b.x, a.y+b.y);}
__device__ __forceinline__ float2 csub(float2 a, float2 b){return make_float2(a.x-b.x, a.y-b.y);}
__device__ __forceinline__ float2 cmul(float2 a, float2 b){
    return make_float2(fmaf(a.x,b.x,-a.y*b.y), fmaf(a.x,b.y,a.y*b.x));
}
__device__ __forceinline__ float2 cmulnegi(float2 a){return make_float2(a.y, -a.x);}   // a * (-i)

// 16-point DFT, natural order in/out, registers only (HW-verified R5/R6).
__device__ __forceinline__ void dft16(float2* z) {
    const float2 W1 = make_float2( 0.92387953251f, -0.38268343236f);
    const float2 W2 = make_float2( 0.70710678119f, -0.70710678119f);
    const float2 W3 = make_float2( 0.38268343236f, -0.92387953251f);
    const float2 W6 = make_float2(-0.70710678119f, -0.70710678119f);
    const float2 W9 = make_float2(-0.92387953251f,  0.38268343236f);
    float2 g[16];
    #pragma unroll
    for (int q = 0; q < 4; q++) {
        float2 t0=z[q], t1=z[4+q], t2=z[8+q], t3=z[12+q];
        float2 A=cadd(t0,t2), B=csub(t0,t2), C=cadd(t1,t3), D=csub(t1,t3);
        g[q]    = cadd(A,C);
        g[4+q]  = make_float2(B.x + D.y, B.y - D.x);
        g[8+q]  = csub(A,C);
        g[12+q] = make_float2(B.x - D.y, B.y + D.x);
    }
    g[4+1] =cmul(g[4+1], W1); g[4+2] =cmul(g[4+2], W2); g[4+3] =cmul(g[4+3], W3);
    g[8+1] =cmul(g[8+1], W2); g[8+2] =cmulnegi(g[8+2]); g[8+3] =cmul(g[8+3], W6);
    g[12+1]=cmul(g[12+1],W3); g[12+2]=cmul(g[12+2],W6);  g[12+3]=cmul(g[12+3],W9);
    #pragma unroll
    for (int r = 0; r < 4; r++) {
        float2 t0=g[4*r], t1=g[4*r+1], t2=g[4*r+2], t3=g[4*r+3];
        float2 A=cadd(t0,t2), B=csub(t0,t2), C=cadd(t1,t3), D=csub(t1,t3);
        z[r]    = cadd(A,C);
        z[r+4]  = make_float2(B.x + D.y, B.y - D.x);
        z[r+8]  = csub(A,C);
        z[r+12] = make_float2(B.x - D.y, B.y + D.x);
    }
}

// Single fused kernel: FFT + mel + chunk-EMA aggregate + decoupled cross-chunk
// prefix + pcen output. Block = (chunk P, batch b), 256 threads = 4 waves.
//
// Phase 1 (as before): 4 wave-private two-for-one 1024-pt FFTs -> spec ->
// sparse mel -> acc; melst (8 frames x 128 mels) staged in LDS; chunk EMA
// aggregate S computed.
//
// Phase 2 (new, replaces the pcen_out kernel): publish S with device-scope
// release + flag; spin-acquire on flags of chunks j<P (same batch); compute
// chunk-entry M = sum_{j<P} D8^(P-1-j) * S_j (independent pipelined loads,
// the verified R5 form); replay 8 frames FROM LDS (mel never touches HBM:
// saves the 10.25 MB write + 10.25 MB read and one kernel launch + gap).
//
// Deadlock safety: every block publishes BEFORE any wait, and waits only on
// lower blockIdx.x within its own blockIdx.y -- the same forward-progress
// assumption rocPRIM's shipped decoupled-lookback scan uses on this hardware
// (x-major dispatch). Flags zeroed by a graph-captured hipMemsetAsync.
__global__ __launch_bounds__(256, 4)
void fft_mel_pcen(const float* __restrict__ x, float* __restrict__ out,
                  float* __restrict__ S, unsigned int* __restrict__ flags,
                  Bins bins) {
    __shared__ float2 wbuf[PPB][1088];      // 34816 B total

    const int tid = threadIdx.x;
    const int w   = tid >> 6;               // wave slot = pair-in-block
    const int u   = tid & 63;
    const int P   = blockIdx.x;             // chunk id 0..78
    const int b   = blockIdx.y;
    const int p   = P * PPB + w;            // global frame-pair

    float acc[4];                           // this lane's 4 mel outputs

    if (p < NPAIRS) {
        float2* buf  = wbuf[w];
        float*  raw  = (float*)&wbuf[w][0]; // raw-sample view (floats 0..1279)
        float*  spec = (float*)&wbuf[w][0]; // aliases buf (safe: see unpack)

        // load samples base..base+1279 (covers frames 2p and 2p+1)
        const float* xb = x + (size_t)b * LSAMP;
        const int base = 512 * p - 512;
        if (p != 0 && p != NPAIRS - 1) {
            // interior: contiguous, 16B-aligned (base = 512(p-1), x 16B-aligned)
            const float* xs = xb + base;
            #pragma unroll
            for (int j = 0; j < 5; j++) {
                const int i = 256 * j + 4 * u;
                float4 v = *reinterpret_cast<const float4*>(xs + i);
                *reinterpret_cast<float4*>(raw + i) = v;
            }
        } else {
            // boundary pairs: scalar with reflect pad
            #pragma unroll
            for (int j = 0; j < 20; j++) {
                const int i = 64 * j + u;
                raw[i] = xb[refl(base + i)];
            }
        }

        float2 z[16];

        // stage 1: z[a] = x[base+64a+u] + i*x[base+64a+u+256]  (two-for-one)
        // raw reads (b32, bank = u%32, conflict-free) complete before the
        // 17u+k writes below are issued (in-order per-wave DS pipe).
        #pragma unroll
        for (int a = 0; a < 16; a++)
            z[a] = make_float2(raw[64*a + u], raw[64*a + u + 256]);
        dft16(z);
        {
            float s, c; __sincosf(-(float)M_PI * (float)u * (1.0f/512.0f), &s, &c);
            float2 w1 = make_float2(c, s), wk = w1;
            #pragma unroll
            for (int k = 1; k < 16; k++) { z[k] = cmul(z[k], wk); wk = cmul(wk, w1); }
        }
        #pragma unroll
        for (int k = 0; k < 16; k++) buf[17*u + k] = z[k];

        // stage 2: u -> (k1=u>>2, bp=u&3); DFT16, twiddle W_1024^{16*bp*k}
        const int k1 = u >> 2, bp = u & 3;
        #pragma unroll
        for (int a = 0; a < 16; a++) z[a] = buf[68*a + 17*bp + k1];
        dft16(z);
        {
            float s, c; __sincosf(-(float)M_PI * (float)bp * (1.0f/32.0f), &s, &c);
            float2 w1 = make_float2(c, s), wk = w1;
            #pragma unroll
            for (int k = 1; k < 16; k++) { z[k] = cmul(z[k], wk); wk = cmul(wk, w1); }
        }
        #pragma unroll
        for (int k = 0; k < 16; k++) buf[68*k + 17*bp + k1] = z[k];

        // stage 3: DFT4 over bp for each (k1,k2a); X[k1 + 16*k2a + 256*k2b]
        #pragma unroll
        for (int j = 0; j < 4; j++) {
            const int c = 64*j + u;
            const int kk1 = c & 15, k2a = c >> 4;
            #pragma unroll
            for (int bq = 0; bq < 4; bq++) z[4*j + bq] = buf[68*k2a + 17*bq + kk1];
        }
        #pragma unroll
        for (int j = 0; j < 4; j++) {
            const int kbase = u + 64*j;
            float2 t0=z[4*j], t1=z[4*j+1], t2=z[4*j+2], t3=z[4*j+3];
            float2 A=cadd(t0,t2), B=csub(t0,t2), C=cadd(t1,t3), D=csub(t1,t3);
            buf[kbase]       = cadd(A,C);
            buf[kbase + 256] = make_float2(B.x + D.y, B.y - D.x);
            buf[kbase + 512] = csub(A,C);
            buf[kbase + 768] = make_float2(B.x - D.y, B.y + D.x);
        }

        // unpack two-for-one + magnitude, REGISTER-STAGED so spec can alias buf:
        // all buf reads complete (into m0/m1) before any spec write is issued.
        float m0[9], m1[9];
        #pragma unroll
        for (int j = 0; j < 9; j++) {
            const int k = 64*j + u;
            if (k <= 512) {
                const int nk = (1024 - k) & 1023;
                float2 Zk = buf[k], Zn = buf[nk];
                float ar = Zk.x + Zn.x, ai = Zk.y - Zn.y;
                float br = Zk.y + Zn.y, bi = Zn.x - Zk.x;
                m0[j] = 0.5f * sqrtf(ar*ar + ai*ai);
                m1[j] = 0.5f * sqrtf(br*br + bi*bi);
            }
        }
        #pragma unroll
        for (int j = 0; j < 9; j++) {
            const int k = 64*j + u;
            if (k <= 512) { spec[k] = m0[j]; spec[NFREQ + k] = m1[j]; }
        }

        // sparse mel (fb synthesized from bin edges); lane -> pf, 4 bands
        // via the balanced band_of map. Inner loops 2-way unrolled with dual
        // accumulators. Band normalization via v_rcp. NOTE: no global mel
        // store anymore -- mel lives only in acc/melst.
        const int r = u & 31, pf = u >> 5;
        const float* sp = spec + pf * NFREQ;
        #pragma unroll
        for (int i = 0; i < 4; i++) {
            const int mm = band_of(i, r);
            const int a = bins.v[mm], bb = bins.v[mm+1], c = bins.v[mm+2];
            float a0 = 0.f;
            if (bb > a) {
                float s0 = 0.f, s1 = 0.f;
                int f = a;
                for (; f + 1 < bb; f += 2) {
                    s0 = fmaf(sp[f],     (float)(f     - a), s0);
                    s1 = fmaf(sp[f + 1], (float)(f + 1 - a), s1);
                }
                if (f < bb) s0 = fmaf(sp[f], (float)(f - a), s0);
                a0 += (s0 + s1) * __builtin_amdgcn_rcpf((float)(bb - a));
            }
            if (c > bb) {
                float s0 = 0.f, s1 = 0.f;
                int f = bb;
                for (; f + 1 < c; f += 2) {
                    s0 = fmaf(sp[f],     (float)(c - f),     s0);
                    s1 = fmaf(sp[f + 1], (float)(c - f - 1), s1);
                }
                if (f < c) s0 = fmaf(sp[f], (float)(c - f), s0);
                a0 += (s0 + s1) * __builtin_amdgcn_rcpf((float)(c - bb));
            }
            acc[i] = a0;
        }
    }
    __syncthreads();                        // all waves done with their spec

    // stage mel into LDS: upper half of wave-0's region (floats 1088..2112),
    // disjoint from wave-0's spec (floats 0..1025). Dead space post-barrier.
    float* melst = (float*)&wbuf[0][544];   // 1024 floats
    if (p < NPAIRS) {
        const int r = u & 31, pf = u >> 5;
        const int fl = 2*w + pf;            // local frame 0..7
        #pragma unroll
        for (int i = 0; i < 4; i++) melst[fl*NMELS + band_of(i, r)] = acc[i];
    }
    __syncthreads();

    // pcen phase A: chunk EMA-from-zero (t=0 seeds exactly) -> publish S.
    if (tid < NMELS) {
        const int t0 = P * 8;
        const int nf = (NFRAMES - t0 < 8) ? NFRAMES - t0 : 8;
        float s = 0.f;
        for (int f = 0; f < nf; f++) {
            float v = melst[f*NMELS + tid];
            s = (t0 + f == 0) ? v : fmaf(0.975f, s, 0.025f * v);
        }
        S[((size_t)b * NCHUNK + P) * NMELS + tid] = s;
        __threadfence();                    // make S visible device-wide
    }
    __syncthreads();                        // all 128 S stores fenced
    if (tid == 0)
        __hip_atomic_store(&flags[(size_t)b * NCHUNK + P], 1u,
                           __ATOMIC_RELEASE, __HIP_MEMORY_SCOPE_AGENT);

    // wait for all predecessor chunks of this batch (publish happened FIRST,
    // and we only wait on lower blockIdx.x -> no circular waits).
    if (tid < P) {
        while (!__hip_atomic_load(&flags[(size_t)b * NCHUNK + tid],
                                  __ATOMIC_ACQUIRE, __HIP_MEMORY_SCOPE_AGENT))
            __builtin_amdgcn_s_sleep(8);
    }
    __syncthreads();
    __threadfence();                        // acquire-side visibility for readers

    // pcen phases B+C: chunk-entry M via weighted sum of published aggregates
    // (independent pipelined loads, 4 parallel accumulators -- verified R5
    // form), then replay 8 frames from LDS and write the output.
    if (tid < NMELS) {
        const int m = tid;
        float D8; { float d = 0.975f; d *= d; d *= d; d *= d; D8 = d; }

        float M = 0.f;
        if (P > 0) {
            const float* Sp = S + (size_t)b * NCHUNK * NMELS + m;
            float D32 = D8 * D8; D32 *= D32;    // D8^4
            float a0 = 0.f, a1 = 0.f, a2 = 0.f, a3 = 0.f;
            float w0 = 1.f, w1 = D8, w2 = D8 * D8, w3 = w2 * D8;
            int j = P - 1;                      // weight of S_j is D8^(P-1-j)
            for (; j >= 3; j -= 4) {
                a0 = fmaf(w0, Sp[(size_t)j       * NMELS], a0);
                a1 = fmaf(w1, Sp[(size_t)(j - 1) * NMELS], a1);
                a2 = fmaf(w2, Sp[(size_t)(j - 2) * NMELS], a2);
                a3 = fmaf(w3, Sp[(size_t)(j - 3) * NMELS], a3);
                w0 *= D32; w1 *= D32; w2 *= D32; w3 *= D32;
            }
            for (; j >= 0; j--) { a0 = fmaf(w0, Sp[(size_t)j * NMELS], a0); w0 *= D8; }
            M = (a0 + a1) + (a2 + a3);
        }

        const int t0 = P * 8;
        float* op = out + ((size_t)b * NFRAMES + t0) * NMELS + m;
        #pragma unroll 8
        for (int f = 0; f < 8; f++) {
            const int t = t0 + f;
            if (t >= NFRAMES) break;
            float v = melst[f * NMELS + m];
            M = (t == 0) ? v : fmaf(0.975f, M, 0.025f * v);
            float inv = __builtin_amdgcn_exp2f(-0.98f * __builtin_amdgcn_logf(M + 1e-6f));
            op[(size_t)f * NMELS] = sqrtf(fmaf(v, inv, 2.0f)) - 1.41421356237f;
        }
    }
}

extern "C" void kernel_launch(void* const* d_in, const int* in_sizes, int n_in,
                              void* d_out, int out_size, void* d_ws, size_t ws_size,
                              hipStream_t stream) {
    const float* x  = (const float*)d_in[0];   // (32, 160000)
    float* out = (float*)d_out;                // (32, 626, 128)

    float* S = (float*)d_ws;                               // 32*79*128 f32
    unsigned int* flags =
        (unsigned int*)(S + (size_t)NBATCH * NCHUNK * NMELS);  // 32*79 u32

    // Host-side bin edges, replicating numpy exactly in double.
    Bins bins;
    {
        const double m_max = 2595.0 * log10(1.0 + 8000.0 / 700.0);
        const double step  = m_max / 129.0;
        for (int i = 0; i < NMELS + 2; i++) {
            double mv = (i == NMELS + 1) ? m_max : (double)i * step;
            double f  = 700.0 * (pow(10.0, mv / 2595.0) - 1.0);
            bins.v[i] = (int)floor((double)(NFREQ - 1) * 2.0 * f / 16000.0);
        }
    }

    // zero the publication flags (workspace arrives poisoned); captured in
    // the graph, so it replays before the kernel every iteration.
    hipMemsetAsync(flags, 0, (size_t)NBATCH * NCHUNK * sizeof(unsigned int),
                   stream);

    dim3 grid(NBLK, NBATCH);
    fft_mel_pcen<<<grid, 256, 0, stream>>>(x, out, S, flags, bins);
}

// Round 7
// 105.474 us; speedup vs baseline: 4.5452x; 4.5452x over previous
//
#include <hip/hip_runtime.h>
#include <math.h>

#define NMELS   128
#define NFRAMES 626
#define NPAIRS  313
#define NBATCH  32
#define LSAMP   160000
#define NFREQ   513                         // 1024/2 + 1
#define PPB     4                           // frame-pairs per block (1 per wave)
#define NBLK    ((NPAIRS + PPB - 1) / PPB)  // 79
#define NCHUNK  NBLK                        // pcen chunk = 8 frames = 1 block

struct Bins { int v[NMELS + 2]; };          // 130 ints = 520 B kernarg

// reflect-pad index (np.pad mode='reflect', no edge repeat)
__device__ __forceinline__ int refl(int i) {
    if (i < 0) i = -i;
    else if (i >= LSAMP) i = 2 * LSAMP - 2 - i;
    return i;
}

// lane r -> band for sub-iteration i. Pairs wide (high-m) with narrow (low-m)
// bands so per-i loop trip counts are near-uniform across the wave (mel band
// widths grow ~geometrically; the old {r,32+r,64+r,96+r} map made the wave
// wait on the widest lane: ~112 exec-masked iterations vs ~40 balanced).
// Bijective cover of 0..127. Verified win: R2->R4 119.2->109.3 us.
__device__ __forceinline__ int band_of(int i, int r) {
    switch (i) {
        case 0:  return r;
        case 1:  return 127 - r;
        case 2:  return 32 + r;
        default: return 95 - r;
    }
}

__device__ __forceinline__ float2 cadd(float2 a, float2 b){return make_float2(a.x+b.x, a.y+b.y);}
__device__ __forceinline__ float2 csub(float2 a, float2 b){return make_float2(a.x-b.x, a.y-b.y);}
__device__ __forceinline__ float2 cmul(float2 a, float2 b){
    return make_float2(fmaf(a.x,b.x,-a.y*b.y), fmaf(a.x,b.y,a.y*b.x));
}
__device__ __forceinline__ float2 cmulnegi(float2 a){return make_float2(a.y, -a.x);}   // a * (-i)

// 16-point DFT, natural order in/out, registers only (HW-verified R5/R6).
__device__ __forceinline__ void dft16(float2* z) {
    const float2 W1 = make_float2( 0.92387953251f, -0.38268343236f);
    const float2 W2 = make_float2( 0.70710678119f, -0.70710678119f);
    const float2 W3 = make_float2( 0.38268343236f, -0.92387953251f);
    const float2 W6 = make_float2(-0.70710678119f, -0.70710678119f);
    const float2 W9 = make_float2(-0.92387953251f,  0.38268343236f);
    float2 g[16];
    #pragma unroll
    for (int q = 0; q < 4; q++) {
        float2 t0=z[q], t1=z[4+q], t2=z[8+q], t3=z[12+q];
        float2 A=cadd(t0,t2), B=csub(t0,t2), C=cadd(t1,t3), D=csub(t1,t3);
        g[q]    = cadd(A,C);
        g[4+q]  = make_float2(B.x + D.y, B.y - D.x);
        g[8+q]  = csub(A,C);
        g[12+q] = make_float2(B.x - D.y, B.y + D.x);
    }
    g[4+1] =cmul(g[4+1], W1); g[4+2] =cmul(g[4+2], W2); g[4+3] =cmul(g[4+3], W3);
    g[8+1] =cmul(g[8+1], W2); g[8+2] =cmulnegi(g[8+2]); g[8+3] =cmul(g[8+3], W6);
    g[12+1]=cmul(g[12+1],W3); g[12+2]=cmul(g[12+2],W6);  g[12+3]=cmul(g[12+3],W9);
    #pragma unroll
    for (int r = 0; r < 4; r++) {
        float2 t0=g[4*r], t1=g[4*r+1], t2=g[4*r+2], t3=g[4*r+3];
        float2 A=cadd(t0,t2), B=csub(t0,t2), C=cadd(t1,t3), D=csub(t1,t3);
        z[r]    = cadd(A,C);
        z[r+4]  = make_float2(B.x + D.y, B.y - D.x);
        z[r+8]  = csub(A,C);
        z[r+12] = make_float2(B.x - D.y, B.y + D.x);
    }
}

// 256-thread block = 4 wave-private FFT frame-pairs = 8 frames = 1 pcen chunk.
// Per wave: four-step 1024 = 16x16x4 FFT, 16 pts/lane in regs, in-place LDS
// exchanges in the wave's OWN 8704 B buffer -> no __syncthreads in FFT path.
// Input staging: interior pairs load the 1280 unique samples as 5 float4/lane
// into the raw-float view of the buffer (no refl, no duplicate fetch of the
// 768-sample overlap); stage 1 assembles (x[n], x[n+256]) pairs from two
// conflict-free b32 reads. Wave-private in-order DS pipe makes the raw->buf
// alias safe (reads precede writes in program order).
// LDS = 34.8 KB/block -> 4 blocks/CU.
//
// NOTE (R6): fusing pcen into this kernel via decoupled-lookback flags was
// tried and regressed 4.5x (spin-wait at device scope serializes; occupancy
// 37%, VALUBusy 6%). The separate-kernel form below is the verified optimum:
// the stream boundary provides the cross-chunk dependency for ~2 us.
__global__ __launch_bounds__(256, 4)
void fft_mel_kernel(const float* __restrict__ x, float* __restrict__ mel,
                    float* __restrict__ S, Bins bins) {
    __shared__ float2 wbuf[PPB][1088];      // 34816 B total

    const int tid = threadIdx.x;
    const int w   = tid >> 6;               // wave slot = pair-in-block
    const int u   = tid & 63;
    const int P   = blockIdx.x;             // chunk id 0..78
    const int b   = blockIdx.y;
    const int p   = P * PPB + w;            // global frame-pair

    float acc[4];                           // this lane's 4 mel outputs

    if (p < NPAIRS) {
        float2* buf  = wbuf[w];
        float*  raw  = (float*)&wbuf[w][0]; // raw-sample view (floats 0..1279)
        float*  spec = (float*)&wbuf[w][0]; // aliases buf (safe: see unpack)

        // load samples base..base+1279 (covers frames 2p and 2p+1)
        const float* xb = x + (size_t)b * LSAMP;
        const int base = 512 * p - 512;
        if (p != 0 && p != NPAIRS - 1) {
            // interior: contiguous, 16B-aligned (base = 512(p-1), x 16B-aligned)
            const float* xs = xb + base;
            #pragma unroll
            for (int j = 0; j < 5; j++) {
                const int i = 256 * j + 4 * u;
                float4 v = *reinterpret_cast<const float4*>(xs + i);
                *reinterpret_cast<float4*>(raw + i) = v;
            }
        } else {
            // boundary pairs: scalar with reflect pad
            #pragma unroll
            for (int j = 0; j < 20; j++) {
                const int i = 64 * j + u;
                raw[i] = xb[refl(base + i)];
            }
        }

        float2 z[16];

        // stage 1: z[a] = x[base+64a+u] + i*x[base+64a+u+256]  (two-for-one)
        // raw reads (b32, bank = u%32, conflict-free) complete before the
        // 17u+k writes below are issued (in-order per-wave DS pipe).
        #pragma unroll
        for (int a = 0; a < 16; a++)
            z[a] = make_float2(raw[64*a + u], raw[64*a + u + 256]);
        dft16(z);
        {
            float s, c; __sincosf(-(float)M_PI * (float)u * (1.0f/512.0f), &s, &c);
            float2 w1 = make_float2(c, s), wk = w1;
            #pragma unroll
            for (int k = 1; k < 16; k++) { z[k] = cmul(z[k], wk); wk = cmul(wk, w1); }
        }
        #pragma unroll
        for (int k = 0; k < 16; k++) buf[17*u + k] = z[k];

        // stage 2: u -> (k1=u>>2, bp=u&3); DFT16, twiddle W_1024^{16*bp*k}
        const int k1 = u >> 2, bp = u & 3;
        #pragma unroll
        for (int a = 0; a < 16; a++) z[a] = buf[68*a + 17*bp + k1];
        dft16(z);
        {
            float s, c; __sincosf(-(float)M_PI * (float)bp * (1.0f/32.0f), &s, &c);
            float2 w1 = make_float2(c, s), wk = w1;
            #pragma unroll
            for (int k = 1; k < 16; k++) { z[k] = cmul(z[k], wk); wk = cmul(wk, w1); }
        }
        #pragma unroll
        for (int k = 0; k < 16; k++) buf[68*k + 17*bp + k1] = z[k];

        // stage 3: DFT4 over bp for each (k1,k2a); X[k1 + 16*k2a + 256*k2b]
        #pragma unroll
        for (int j = 0; j < 4; j++) {
            const int c = 64*j + u;
            const int kk1 = c & 15, k2a = c >> 4;
            #pragma unroll
            for (int bq = 0; bq < 4; bq++) z[4*j + bq] = buf[68*k2a + 17*bq + kk1];
        }
        #pragma unroll
        for (int j = 0; j < 4; j++) {
            const int kbase = u + 64*j;
            float2 t0=z[4*j], t1=z[4*j+1], t2=z[4*j+2], t3=z[4*j+3];
            float2 A=cadd(t0,t2), B=csub(t0,t2), C=cadd(t1,t3), D=csub(t1,t3);
            buf[kbase]       = cadd(A,C);
            buf[kbase + 256] = make_float2(B.x + D.y, B.y - D.x);
            buf[kbase + 512] = csub(A,C);
            buf[kbase + 768] = make_float2(B.x - D.y, B.y + D.x);
        }

        // unpack two-for-one + magnitude, REGISTER-STAGED so spec can alias buf:
        // all buf reads complete (into m0/m1) before any spec write is issued.
        float m0[9], m1[9];
        #pragma unroll
        for (int j = 0; j < 9; j++) {
            const int k = 64*j + u;
            if (k <= 512) {
                const int nk = (1024 - k) & 1023;
                float2 Zk = buf[k], Zn = buf[nk];
                float ar = Zk.x + Zn.x, ai = Zk.y - Zn.y;
                float br = Zk.y + Zn.y, bi = Zn.x - Zk.x;
                m0[j] = 0.5f * sqrtf(ar*ar + ai*ai);
                m1[j] = 0.5f * sqrtf(br*br + bi*bi);
            }
        }
        #pragma unroll
        for (int j = 0; j < 9; j++) {
            const int k = 64*j + u;
            if (k <= 512) { spec[k] = m0[j]; spec[NFREQ + k] = m1[j]; }
        }

        // sparse mel (fb synthesized from bin edges); lane -> pf, 4 bands
        // via the balanced band_of map. Inner loops 2-way unrolled with dual
        // accumulators (halves loop overhead, splits the FMA dep chain).
        // Band normalization via v_rcp (<=1 ulp on small-int denominators).
        const int r = u & 31, pf = u >> 5;
        const float* sp = spec + pf * NFREQ;
        #pragma unroll
        for (int i = 0; i < 4; i++) {
            const int mm = band_of(i, r);
            const int a = bins.v[mm], bb = bins.v[mm+1], c = bins.v[mm+2];
            float a0 = 0.f;
            if (bb > a) {
                float s0 = 0.f, s1 = 0.f;
                int f = a;
                for (; f + 1 < bb; f += 2) {
                    s0 = fmaf(sp[f],     (float)(f     - a), s0);
                    s1 = fmaf(sp[f + 1], (float)(f + 1 - a), s1);
                }
                if (f < bb) s0 = fmaf(sp[f], (float)(f - a), s0);
                a0 += (s0 + s1) * __builtin_amdgcn_rcpf((float)(bb - a));
            }
            if (c > bb) {
                float s0 = 0.f, s1 = 0.f;
                int f = bb;
                for (; f + 1 < c; f += 2) {
                    s0 = fmaf(sp[f],     (float)(c - f),     s0);
                    s1 = fmaf(sp[f + 1], (float)(c - f - 1), s1);
                }
                if (f < c) s0 = fmaf(sp[f], (float)(c - f), s0);
                a0 += (s0 + s1) * __builtin_amdgcn_rcpf((float)(c - bb));
            }
            acc[i] = a0;
            mel[((size_t)b * NFRAMES + 2*p + pf) * NMELS + mm] = a0;
        }
    }
    __syncthreads();                        // all waves done with their spec

    // stage mel into LDS: upper half of wave-0's region (floats 1088..2112),
    // disjoint from wave-0's spec (floats 0..1025). Dead space post-barrier.
    float* melst = (float*)&wbuf[0][544];   // 1024 floats
    if (p < NPAIRS) {
        const int r = u & 31, pf = u >> 5;
        const int fl = 2*w + pf;            // local frame 0..7
        #pragma unroll
        for (int i = 0; i < 4; i++) melst[fl*NMELS + band_of(i, r)] = acc[i];
    }
    __syncthreads();

    // pcen phase A: chunk EMA-from-zero (t=0 seeds exactly)
    if (tid < NMELS) {
        const int t0 = P * 8;
        const int nf = (NFRAMES - t0 < 8) ? NFRAMES - t0 : 8;
        float s = 0.f;
        for (int f = 0; f < nf; f++) {
            float v = melst[f*NMELS + tid];
            s = (t0 + f == 0) ? v : fmaf(0.975f, s, 0.025f * v);
        }
        S[((size_t)b * NCHUNK + P) * NMELS + tid] = s;
    }
}

// PCEN phases B+C fused: block = (chunk c, batch b), 128 threads = m.
// Chunk-entry M = sum_{j<c} D8^(c-1-j) * S[b,j,m] -- the exclusive affine
// scan rewritten as a weighted sum with PRECOMPUTABLE weights: all loads
// are independent (pipeline fully, 4 parallel accumulators), unlike the
// R0 fusion attempt whose dependent fma chain serialized ~78 L2 latencies
// and regressed +4 us. Weight-update muls ride hidden under the loads.
// S is 1.3 MB (L2/L3-resident); the ~50 MB of re-reads overlap the
// HBM-bound output phase. Removes pcen_scan launch + Mstart round-trip.
__global__ __launch_bounds__(128)
void pcen_out(const float* __restrict__ mel, const float* __restrict__ S,
              float* __restrict__ out) {
    const int m = threadIdx.x;
    const int c = blockIdx.x;               // 0..78
    const int b = blockIdx.y;

    float D8; { float d = 0.975f; d *= d; d *= d; d *= d; D8 = d; }

    float M = 0.f;
    if (c > 0) {
        const float* Sp = S + (size_t)b * NCHUNK * NMELS + m;
        float D32 = D8 * D8; D32 *= D32;    // D8^4
        float a0 = 0.f, a1 = 0.f, a2 = 0.f, a3 = 0.f;
        float w0 = 1.f, w1 = D8, w2 = D8 * D8, w3 = w2 * D8;
        int j = c - 1;                      // weight of S_j is D8^(c-1-j)
        for (; j >= 3; j -= 4) {
            a0 = fmaf(w0, Sp[(size_t)j       * NMELS], a0);
            a1 = fmaf(w1, Sp[(size_t)(j - 1) * NMELS], a1);
            a2 = fmaf(w2, Sp[(size_t)(j - 2) * NMELS], a2);
            a3 = fmaf(w3, Sp[(size_t)(j - 3) * NMELS], a3);
            w0 *= D32; w1 *= D32; w2 *= D32; w3 *= D32;
        }
        for (; j >= 0; j--) { a0 = fmaf(w0, Sp[(size_t)j * NMELS], a0); w0 *= D8; }
        M = (a0 + a1) + (a2 + a3);
    }

    // replay 8 frames from the chunk-entry state (t==0 seeds exactly).
    // v/pow(M+eps,0.98) = v*2^(-0.98*log2(M+eps)) via HW v_exp/v_log
    // (rel err ~2e-6, tolerance 3.9e-3).
    const int t0 = c * 8;
    const int tend = (t0 + 8 < NFRAMES) ? t0 + 8 : NFRAMES;
    const float* mp = mel + (size_t)b * NFRAMES * NMELS + m;
    float*       op = out + (size_t)b * NFRAMES * NMELS + m;
    #pragma unroll 8
    for (int t = t0; t < tend; t++) {
        float v = mp[(size_t)t * NMELS];
        M = (t == 0) ? v : fmaf(0.975f, M, 0.025f * v);
        float inv = __builtin_amdgcn_exp2f(-0.98f * __builtin_amdgcn_logf(M + 1e-6f));
        op[(size_t)t * NMELS] = sqrtf(fmaf(v, inv, 2.0f)) - 1.41421356237f;
    }
}

extern "C" void kernel_launch(void* const* d_in, const int* in_sizes, int n_in,
                              void* d_out, int out_size, void* d_ws, size_t ws_size,
                              hipStream_t stream) {
    const float* x  = (const float*)d_in[0];   // (32, 160000)
    float* out = (float*)d_out;                // (32, 626, 128)

    float* mel = (float*)d_ws;                             // 32*626*128 f32
    float* S   = mel + (size_t)NBATCH * NFRAMES * NMELS;   // 32*79*128 f32

    // Host-side bin edges, replicating numpy exactly in double.
    Bins bins;
    {
        const double m_max = 2595.0 * log10(1.0 + 8000.0 / 700.0);
        const double step  = m_max / 129.0;
        for (int i = 0; i < NMELS + 2; i++) {
            double mv = (i == NMELS + 1) ? m_max : (double)i * step;
            double f  = 700.0 * (pow(10.0, mv / 2595.0) - 1.0);
            bins.v[i] = (int)floor((double)(NFREQ - 1) * 2.0 * f / 16000.0);
        }
    }

    dim3 grid1(NBLK, NBATCH);
    fft_mel_kernel<<<grid1, 256, 0, stream>>>(x, mel, S, bins);

    dim3 grid2(NCHUNK, NBATCH);
    pcen_out<<<grid2, 128, 0, stream>>>(mel, S, out);
}